// Round 17
// baseline (188.521 us; speedup 1.0000x reference)
//
#include <hip/hip_runtime.h>
#include <hip/hip_bf16.h>
#include <stdint.h>

typedef __attribute__((ext_vector_type(8))) __bf16 bf16x8;
typedef __attribute__((ext_vector_type(4))) float f32x4;

#define GLOAD_LDS16(gp, lp) __builtin_amdgcn_global_load_lds( \
    (const __attribute__((address_space(1))) void*)(gp),      \
    (__attribute__((address_space(3))) void*)(lp), 16, 0, 0)

__device__ __forceinline__ uint16_t f2bf_rne(float f) {
  uint32_t u = __float_as_uint(f);
  u += 0x7FFFu + ((u >> 16) & 1u);
  return (uint16_t)(u >> 16);
}

// ---------------- fused f32 -> bf16 conversion (z, Wq, Wk in one launch) ----
__global__ __launch_bounds__(256) void cvt_all(
    const float* __restrict__ z, const float* __restrict__ wq,
    const float* __restrict__ wk, uint16_t* __restrict__ zb,
    uint16_t* __restrict__ wqb, uint16_t* __restrict__ wkb) {
  const int bid = blockIdx.x;
  const float* src;
  uint16_t* dst;
  int i;
  if (bid < 4096)        { src = z;  dst = zb;  i = bid * 256 + threadIdx.x; }
  else if (bid < 12288)  { src = wq; dst = wqb; i = (bid - 4096) * 256 + threadIdx.x; }
  else                   { src = wk; dst = wkb; i = (bid - 12288) * 256 + threadIdx.x; }
  const float4* s4 = (const float4*)src;
  float4 a = s4[2 * i], b = s4[2 * i + 1];
  union { uint16_t u[8]; uint4 v; } o;
  o.u[0] = f2bf_rne(a.x); o.u[1] = f2bf_rne(a.y);
  o.u[2] = f2bf_rne(a.z); o.u[3] = f2bf_rne(a.w);
  o.u[4] = f2bf_rne(b.x); o.u[5] = f2bf_rne(b.y);
  o.u[6] = f2bf_rne(b.z); o.u[7] = f2bf_rne(b.w);
  ((uint4*)dst)[i] = o.v;
}

// ---------------- bf16 GEMM, 256x256 tile, 16 waves, ring-4 BK=32 -----------
// R16 = R6's gemm VERBATIM (the measured optimum: 114.8us, MfmaUtil 56%,
// zero conflicts, zero spill). R7-R15 restructures all lost to it.
#define PH_BAR() do { asm volatile("" ::: "memory");            \
                      __builtin_amdgcn_s_barrier();             \
                      asm volatile("" ::: "memory"); } while (0)

#define KTILE(kt, DO_STAGE)                                                    \
  do {                                                                         \
    const char* Ab_ = lds + ((kt) & 3) * 32768;                                \
    const char* Bb_ = Ab_ + 16384;                                             \
    bf16x8 aa[4], bb[4];                                                       \
    _Pragma("unroll")                                                          \
    for (int n_ = 0; n_ < 4; ++n_)                                             \
      bb[n_] = *(const bf16x8*)(Bb_ + boff + n_ * 1024);                       \
    _Pragma("unroll")                                                          \
    for (int m_ = 0; m_ < 4; ++m_)                                             \
      aa[m_] = *(const bf16x8*)(Ab_ + aoff + m_ * 1024);                       \
    if (DO_STAGE) {                                                            \
      const int ss_ = ((kt) + 3) & 3;                                          \
      GLOAD_LDS16(aptr + (size_t)((kt) + 3) * 32, lds + ss_ * 32768 + t16);    \
      GLOAD_LDS16(bptr + (size_t)((kt) + 3) * 32,                              \
                  lds + ss_ * 32768 + 16384 + t16);                            \
    }                                                                          \
    __builtin_amdgcn_s_setprio(1);                                             \
    _Pragma("unroll")                                                          \
    for (int m_ = 0; m_ < 4; ++m_)                                             \
      _Pragma("unroll")                                                        \
      for (int n_ = 0; n_ < 4; ++n_)                                           \
        acc[m_][n_] = __builtin_amdgcn_mfma_f32_16x16x32_bf16(                 \
            aa[m_], bb[n_], acc[m_][n_], 0, 0, 0);                             \
    __builtin_amdgcn_s_setprio(0);                                             \
  } while (0)

__global__ __launch_bounds__(1024, 4) void gemm_qk16(
    const uint16_t* __restrict__ A,
    const uint16_t* __restrict__ Bq, const uint16_t* __restrict__ Bk,
    uint16_t* __restrict__ Cq, uint16_t* __restrict__ Ck) {
  extern __shared__ char lds[];  // 131072 bytes: 4 ring slots x (A 16K + B 16K)

  const int gid = blockIdx.x;
  const int xcd = gid & 7;
  const int idx = gid >> 3;          // 0..31
  const int which = idx & 1;
  const int r = idx >> 1;            // 0..15
  const int tm = (xcd & 1) * 4 + (r & 3);
  const int tn = (xcd >> 1) * 4 + (r >> 2);

  const uint16_t* Bmat = which ? Bk : Bq;
  uint16_t* C = which ? Ck : Cq;
  const int m0 = tm * 256, n0 = tn * 256;

  const int t = threadIdx.x;
  const int lane = t & 63;
  const int w = t >> 6;              // 0..15
  const int wm = w >> 2, wn = w & 3; // 4x4 wave grid, each 64x64 output
  const int t16 = t * 16;

  const int gsw = (((t & 3) ^ ((t >> 3) & 3)) * 8);
  const uint16_t* aptr = A    + (size_t)(m0 + (t >> 2)) * 4096 + gsw;
  const uint16_t* bptr = Bmat + (size_t)(n0 + (t >> 2)) * 4096 + gsw;

  const int sl = ((lane >> 4) ^ ((lane & 15) >> 1)) & 3;
  const int aoff = (wm * 64 + (lane & 15)) * 64 + sl * 16;
  const int boff = (wn * 64 + (lane & 15)) * 64 + sl * 16;

  f32x4 acc[4][4] = {};

#pragma unroll
  for (int p = 0; p < 3; ++p) {
    GLOAD_LDS16(aptr + (size_t)p * 32, lds + p * 32768 + t16);
    GLOAD_LDS16(bptr + (size_t)p * 32, lds + p * 32768 + 16384 + t16);
  }
  asm volatile("s_waitcnt vmcnt(4)" ::: "memory");
  PH_BAR();

  for (int kt = 0; kt < 125; ++kt) {
    KTILE(kt, 1);
    asm volatile("s_waitcnt vmcnt(4)" ::: "memory");
    PH_BAR();
  }
  KTILE(125, 0);
  asm volatile("s_waitcnt vmcnt(2)" ::: "memory");
  PH_BAR();
  KTILE(126, 0);
  asm volatile("s_waitcnt vmcnt(0)" ::: "memory");
  PH_BAR();
  KTILE(127, 0);

  // epilogue: C/D layout col=lane&15, row=(lane>>4)*4+j ; store bf16
  const int colb = n0 + wn * 64 + (lane & 15);
  const int rowb = m0 + wm * 64 + (lane >> 4) * 4;
#pragma unroll
  for (int m_ = 0; m_ < 4; ++m_)
#pragma unroll
    for (int n_ = 0; n_ < 4; ++n_)
#pragma unroll
      for (int j = 0; j < 4; ++j)
        C[(size_t)(rowb + m_ * 16 + j) * 4096 + colb + n_ * 16] =
            f2bf_rne(acc[m_][n_][j]);
}

// ---------------- MFMA scores + softmax -> attn[256][64][64] f32 ------------
__device__ __forceinline__ bf16x8 load_frag_rot(const uint16_t* buf,
                                                int ij, int thb) {
  union { uint16_t u[8]; bf16x8 v; } r;
#pragma unroll
  for (int e = 0; e < 8; ++e) {
    const int th = thb + e;
    const int rot = (th + 2 * (th >> 3)) & 7;
    const int irot = (ij + rot * 8) & 63;
    r.u[e] = buf[th * 64 + irot];
  }
  return r.v;
}

__global__ __launch_bounds__(256) void attn_scores_mfma(
    const uint16_t* __restrict__ Qb, const uint16_t* __restrict__ Kb,
    float* __restrict__ attn) {
  const int n = blockIdx.x;
  __shared__ uint16_t q_l[2][4096];
  __shared__ uint16_t k_l[2][4096];
  __shared__ float scores_l[64 * 68];

  const int t = threadIdx.x;
  const int lane = t & 63;
  const int w = t >> 6;
  const int i0w = (w >> 1) * 32, j0w = (w & 1) * 32;

  const uint16_t* Qn = Qb + (size_t)n * 32768;
  const uint16_t* Kn = Kb + (size_t)n * 32768;

  const int g1 = t, g2 = t + 256;
  const int th1 = g1 >> 3, th2 = g2 >> 3;
  const int s1 = (((g1 & 7) - ((th1 + 2 * (th1 >> 3)) & 7)) & 7);
  const int s2 = (((g2 & 7) - ((th2 + 2 * (th2 >> 3)) & 7)) & 7);
  const size_t so1 = (size_t)th1 * 64 + s1 * 8;
  const size_t so2 = (size_t)th2 * 64 + s2 * 8;

#define STAGE_CH(bf, cm)                                                    \
  do {                                                                      \
    const size_t co_ = (size_t)(cm) * 4096;                                 \
    GLOAD_LDS16(Qn + co_ + so1, (char*)&q_l[bf][0] + g1 * 16);              \
    GLOAD_LDS16(Qn + co_ + so2, (char*)&q_l[bf][0] + g2 * 16);              \
    GLOAD_LDS16(Kn + co_ + so1, (char*)&k_l[bf][0] + g1 * 16);              \
    GLOAD_LDS16(Kn + co_ + so2, (char*)&k_l[bf][0] + g2 * 16);              \
  } while (0)

  f32x4 acc[2][2] = {};

  STAGE_CH(0, 0);
  asm volatile("s_waitcnt vmcnt(0)" ::: "memory");
  __syncthreads();

  for (int cm = 0; cm < 8; ++cm) {
    const int bf = cm & 1;
    if (cm < 7) STAGE_CH(bf ^ 1, cm + 1);
#pragma unroll
    for (int ks = 0; ks < 2; ++ks) {
      const int thb = ks * 32 + (lane >> 4) * 8;
      bf16x8 aa0 = load_frag_rot(&q_l[bf][0], i0w + (lane & 15), thb);
      bf16x8 aa1 = load_frag_rot(&q_l[bf][0], i0w + 16 + (lane & 15), thb);
      bf16x8 bb0 = load_frag_rot(&k_l[bf][0], j0w + (lane & 15), thb);
      bf16x8 bb1 = load_frag_rot(&k_l[bf][0], j0w + 16 + (lane & 15), thb);
      acc[0][0] = __builtin_amdgcn_mfma_f32_16x16x32_bf16(aa0, bb0, acc[0][0], 0, 0, 0);
      acc[0][1] = __builtin_amdgcn_mfma_f32_16x16x32_bf16(aa0, bb1, acc[0][1], 0, 0, 0);
      acc[1][0] = __builtin_amdgcn_mfma_f32_16x16x32_bf16(aa1, bb0, acc[1][0], 0, 0, 0);
      acc[1][1] = __builtin_amdgcn_mfma_f32_16x16x32_bf16(aa1, bb1, acc[1][1], 0, 0, 0);
    }
    asm volatile("s_waitcnt vmcnt(0)" ::: "memory");
    __syncthreads();
  }
#undef STAGE_CH

#pragma unroll
  for (int fi = 0; fi < 2; ++fi)
#pragma unroll
    for (int fj = 0; fj < 2; ++fj)
#pragma unroll
      for (int jr = 0; jr < 4; ++jr) {
        const int i = i0w + fi * 16 + (lane >> 4) * 4 + jr;
        const int j = j0w + fj * 16 + (lane & 15);
        scores_l[i * 68 + j] = acc[fi][fj][jr];
      }
  __syncthreads();

  {
    const int i = t >> 2, jg = t & 3;
    float pv[16];
    *(float4*)(pv + 0)  = *(const float4*)&scores_l[i * 68 + jg * 16 + 0];
    *(float4*)(pv + 4)  = *(const float4*)&scores_l[i * 68 + jg * 16 + 4];
    *(float4*)(pv + 8)  = *(const float4*)&scores_l[i * 68 + jg * 16 + 8];
    *(float4*)(pv + 12) = *(const float4*)&scores_l[i * 68 + jg * 16 + 12];
    float m = pv[0];
#pragma unroll
    for (int q = 1; q < 16; ++q) m = fmaxf(m, pv[q]);
    m = fmaxf(m, __shfl_xor(m, 1, 64));
    m = fmaxf(m, __shfl_xor(m, 2, 64));
    const float sc = 0.044194173824159216f * 1.4426950408889634f;
    float e[16];
    float ssum = 0.f;
#pragma unroll
    for (int q = 0; q < 16; ++q) {
      e[q] = exp2f((pv[q] - m) * sc);
      ssum += e[q];
    }
    ssum += __shfl_xor(ssum, 1, 64);
    ssum += __shfl_xor(ssum, 2, 64);
    const float inv = 1.0f / ssum;
    float ov[16];
#pragma unroll
    for (int q = 0; q < 16; ++q) ov[q] = e[q] * inv;
    float* dst = attn + (size_t)n * 4096 + i * 64 + jg * 16;
    *(float4*)(dst + 0)  = *(float4*)(ov + 0);
    *(float4*)(dst + 4)  = *(float4*)(ov + 4);
    *(float4*)(dst + 8)  = *(float4*)(ov + 8);
    *(float4*)(dst + 12) = *(float4*)(ov + 12);
  }
}

// ---------------- ctx via MFMA: V = Wv@x-slab ; out = V@attn ; leaky --------
// R16 rewrite: old ctx was LDS-bound (~4.5 GB LDS traffic from scalar b32
// re-reads, ~57us). MFMA fragment reuse cuts LDS bytes ~17x. Layouts (all
// bf16, rows padded to 72 elems = 144 B -> frag reads 2-way conflict-free):
//   xw[ul][cc], wv[e][cc], at[j][e]; MFMA1 D1[e][u] -> vt[u][e] (transposed
//   ushort4 store); MFMA2 D2[u][j]; leaky; float4 scatter (u contig in jr).
__global__ __launch_bounds__(256) void ctx_mfma(
    const float* __restrict__ x, const float* __restrict__ Wv,
    const float* __restrict__ attn, float* __restrict__ out) {
  const int n = blockIdx.x >> 3, ut = blockIdx.x & 7;
  const int b = n >> 3, g = n & 7;
  const int u0 = ut * 64;
  __shared__ uint16_t xw_l[64 * 72];
  __shared__ uint16_t wv_l[64 * 72];
  __shared__ uint16_t at_l[64 * 72];
  __shared__ uint16_t vt_l[64 * 72];
  const int t = threadIdx.x;
  const int lane = t & 63;
  const int w = t >> 6;

  {  // x[b, cc, g*512+u0+ul] -> xw_l[ul][cc]
    const float* xbase = x + (size_t)b * 262144 + (size_t)g * 512 + u0;
    const int cc = t >> 4, ul4 = (t & 15) * 4;
#pragma unroll
    for (int r = 0; r < 4; ++r) {
      int c = cc + r * 16;
      float4 v = *(const float4*)&xbase[(size_t)c * 4096 + ul4];
      xw_l[(ul4 + 0) * 72 + c] = f2bf_rne(v.x);
      xw_l[(ul4 + 1) * 72 + c] = f2bf_rne(v.y);
      xw_l[(ul4 + 2) * 72 + c] = f2bf_rne(v.z);
      xw_l[(ul4 + 3) * 72 + c] = f2bf_rne(v.w);
    }
  }
  {  // Wv[e][cc] -> wv_l[e][cc]
    const int e = t >> 4, cc4 = (t & 15) * 4;
#pragma unroll
    for (int r = 0; r < 4; ++r) {
      int ee = e + r * 16;
      float4 v = *(const float4*)&Wv[ee * 64 + cc4];
      ushort4 p;
      p.x = f2bf_rne(v.x); p.y = f2bf_rne(v.y);
      p.z = f2bf_rne(v.z); p.w = f2bf_rne(v.w);
      *(ushort4*)&wv_l[ee * 72 + cc4] = p;
    }
  }
  {  // attn[n][e][j] -> at_l[j][e]
    const float* an = attn + (size_t)n * 4096;
    const int e = t >> 4, j4 = (t & 15) * 4;
#pragma unroll
    for (int r = 0; r < 4; ++r) {
      int ee = e + r * 16;
      float4 v = *(const float4*)&an[ee * 64 + j4];
      at_l[(j4 + 0) * 72 + ee] = f2bf_rne(v.x);
      at_l[(j4 + 1) * 72 + ee] = f2bf_rne(v.y);
      at_l[(j4 + 2) * 72 + ee] = f2bf_rne(v.z);
      at_l[(j4 + 3) * 72 + ee] = f2bf_rne(v.w);
    }
  }
  __syncthreads();

  // MFMA1: D1[e][u] = sum_cc Wv[e][cc] * x[cc][u]; wave w owns e-tile w
  f32x4 acc1[4] = {};
#pragma unroll
  for (int ks = 0; ks < 2; ++ks) {
    bf16x8 a1 = *(const bf16x8*)&wv_l[(w * 16 + (lane & 15)) * 72 +
                                      ks * 32 + (lane >> 4) * 8];
#pragma unroll
    for (int nt = 0; nt < 4; ++nt) {
      bf16x8 b1 = *(const bf16x8*)&xw_l[(nt * 16 + (lane & 15)) * 72 +
                                        ks * 32 + (lane >> 4) * 8];
      acc1[nt] = __builtin_amdgcn_mfma_f32_16x16x32_bf16(a1, b1, acc1[nt], 0, 0, 0);
    }
  }
  // store V transposed: vt_l[u][e], 4 consecutive e per lane -> ushort4
#pragma unroll
  for (int nt = 0; nt < 4; ++nt) {
    int u = nt * 16 + (lane & 15);
    int e0 = w * 16 + (lane >> 4) * 4;
    ushort4 p;
    p.x = f2bf_rne(acc1[nt][0]); p.y = f2bf_rne(acc1[nt][1]);
    p.z = f2bf_rne(acc1[nt][2]); p.w = f2bf_rne(acc1[nt][3]);
    *(ushort4*)&vt_l[u * 72 + e0] = p;
  }
  __syncthreads();

  // MFMA2: D2[u][j] = sum_e V[u][e] * attn[e][j]; wave w owns u-tile w
  f32x4 acc2[4] = {};
#pragma unroll
  for (int ks = 0; ks < 2; ++ks) {
    bf16x8 a2 = *(const bf16x8*)&vt_l[(w * 16 + (lane & 15)) * 72 +
                                      ks * 32 + (lane >> 4) * 8];
#pragma unroll
    for (int nt = 0; nt < 4; ++nt) {
      bf16x8 b2 = *(const bf16x8*)&at_l[(nt * 16 + (lane & 15)) * 72 +
                                        ks * 32 + (lane >> 4) * 8];
      acc2[nt] = __builtin_amdgcn_mfma_f32_16x16x32_bf16(a2, b2, acc2[nt], 0, 0, 0);
    }
  }
  // epilogue: leaky + scatter; out[b, g*8+j/8, (j%8)*512 + u0 + u]
  float* ob = out + (size_t)b * 262144 + (size_t)g * 8 * 4096;
#pragma unroll
  for (int nt = 0; nt < 4; ++nt) {
    int j = nt * 16 + (lane & 15);
    int us = w * 16 + (lane >> 4) * 4;
    float4 o;
    o.x = acc2[nt][0] > 0.f ? acc2[nt][0] : 0.2f * acc2[nt][0];
    o.y = acc2[nt][1] > 0.f ? acc2[nt][1] : 0.2f * acc2[nt][1];
    o.z = acc2[nt][2] > 0.f ? acc2[nt][2] : 0.2f * acc2[nt][2];
    o.w = acc2[nt][3] > 0.f ? acc2[nt][3] : 0.2f * acc2[nt][3];
    *(float4*)&ob[(size_t)(j >> 3) * 4096 + (size_t)(j & 7) * 512 + u0 + us] = o;
  }
}

extern "C" void kernel_launch(void* const* d_in, const int* in_sizes, int n_in,
                              void* d_out, int out_size, void* d_ws, size_t ws_size,
                              hipStream_t stream) {
  const float* z  = (const float*)d_in[0];
  const float* x  = (const float*)d_in[1];
  const float* Wq = (const float*)d_in[2];
  const float* Wk = (const float*)d_in[3];
  const float* Wv = (const float*)d_in[4];
  float* out = (float*)d_out;

  char* ws = (char*)d_ws;
  uint16_t* zb   = (uint16_t*)(ws);                  // 16 MB bf16 z
  uint16_t* wqb  = (uint16_t*)(ws + 16777216);       // 32 MB bf16 Wq
  uint16_t* wkb  = (uint16_t*)(ws + 50331648);       // 32 MB bf16 Wk
  uint16_t* qbo  = (uint16_t*)(ws + 83886080);       // 16 MB bf16 Q
  uint16_t* kbo  = (uint16_t*)(ws + 100663296);      // 16 MB bf16 K
  float*    attn = (float*)(ws + 117440512);         // 4 MB f32

  cvt_all<<<20480, 256, 0, stream>>>(z, Wq, Wk, zb, wqb, wkb);

  (void)hipFuncSetAttribute((const void*)gemm_qk16,
                            hipFuncAttributeMaxDynamicSharedMemorySize, 131072);
  gemm_qk16<<<256, 1024, 131072, stream>>>(zb, wqb, wkb, qbo, kbo);

  attn_scores_mfma<<<256, 256, 0, stream>>>(qbo, kbo, attn);
  ctx_mfma<<<2048, 256, 0, stream>>>(x, Wv, attn, out);
}

// Round 18
// 188.088 us; speedup vs baseline: 1.0023x; 1.0023x over previous
//
#include <hip/hip_runtime.h>
#include <hip/hip_bf16.h>
#include <stdint.h>

typedef __attribute__((ext_vector_type(8))) __bf16 bf16x8;
typedef __attribute__((ext_vector_type(4))) float f32x4;

#define GLOAD_LDS16(gp, lp) __builtin_amdgcn_global_load_lds( \
    (const __attribute__((address_space(1))) void*)(gp),      \
    (__attribute__((address_space(3))) void*)(lp), 16, 0, 0)

__device__ __forceinline__ uint16_t f2bf_rne(float f) {
  uint32_t u = __float_as_uint(f);
  u += 0x7FFFu + ((u >> 16) & 1u);
  return (uint16_t)(u >> 16);
}

// ---------------- fused f32 -> bf16 conversion (z, Wq, Wk in one launch) ----
__global__ __launch_bounds__(256) void cvt_all(
    const float* __restrict__ z, const float* __restrict__ wq,
    const float* __restrict__ wk, uint16_t* __restrict__ zb,
    uint16_t* __restrict__ wqb, uint16_t* __restrict__ wkb) {
  const int bid = blockIdx.x;
  const float* src;
  uint16_t* dst;
  int i;
  if (bid < 4096)        { src = z;  dst = zb;  i = bid * 256 + threadIdx.x; }
  else if (bid < 12288)  { src = wq; dst = wqb; i = (bid - 4096) * 256 + threadIdx.x; }
  else                   { src = wk; dst = wkb; i = (bid - 12288) * 256 + threadIdx.x; }
  const float4* s4 = (const float4*)src;
  float4 a = s4[2 * i], b = s4[2 * i + 1];
  union { uint16_t u[8]; uint4 v; } o;
  o.u[0] = f2bf_rne(a.x); o.u[1] = f2bf_rne(a.y);
  o.u[2] = f2bf_rne(a.z); o.u[3] = f2bf_rne(a.w);
  o.u[4] = f2bf_rne(b.x); o.u[5] = f2bf_rne(b.y);
  o.u[6] = f2bf_rne(b.z); o.u[7] = f2bf_rne(b.w);
  ((uint4*)dst)[i] = o.v;
}

// ---------------- bf16 GEMM, 256x256 tile, 16 waves, ring-4 BK=32 -----------
// R16 = R6's gemm VERBATIM (the measured optimum: 114.8us, MfmaUtil 56%,
// zero conflicts, zero spill). R7-R15 restructures all lost to it.
#define PH_BAR() do { asm volatile("" ::: "memory");            \
                      __builtin_amdgcn_s_barrier();             \
                      asm volatile("" ::: "memory"); } while (0)

#define KTILE(kt, DO_STAGE)                                                    \
  do {                                                                         \
    const char* Ab_ = lds + ((kt) & 3) * 32768;                                \
    const char* Bb_ = Ab_ + 16384;                                             \
    bf16x8 aa[4], bb[4];                                                       \
    _Pragma("unroll")                                                          \
    for (int n_ = 0; n_ < 4; ++n_)                                             \
      bb[n_] = *(const bf16x8*)(Bb_ + boff + n_ * 1024);                       \
    _Pragma("unroll")                                                          \
    for (int m_ = 0; m_ < 4; ++m_)                                             \
      aa[m_] = *(const bf16x8*)(Ab_ + aoff + m_ * 1024);                       \
    if (DO_STAGE) {                                                            \
      const int ss_ = ((kt) + 3) & 3;                                          \
      GLOAD_LDS16(aptr + (size_t)((kt) + 3) * 32, lds + ss_ * 32768 + t16);    \
      GLOAD_LDS16(bptr + (size_t)((kt) + 3) * 32,                              \
                  lds + ss_ * 32768 + 16384 + t16);                            \
    }                                                                          \
    __builtin_amdgcn_s_setprio(1);                                             \
    _Pragma("unroll")                                                          \
    for (int m_ = 0; m_ < 4; ++m_)                                             \
      _Pragma("unroll")                                                        \
      for (int n_ = 0; n_ < 4; ++n_)                                           \
        acc[m_][n_] = __builtin_amdgcn_mfma_f32_16x16x32_bf16(                 \
            aa[m_], bb[n_], acc[m_][n_], 0, 0, 0);                             \
    __builtin_amdgcn_s_setprio(0);                                             \
  } while (0)

__global__ __launch_bounds__(1024, 4) void gemm_qk16(
    const uint16_t* __restrict__ A,
    const uint16_t* __restrict__ Bq, const uint16_t* __restrict__ Bk,
    uint16_t* __restrict__ Cq, uint16_t* __restrict__ Ck) {
  extern __shared__ char lds[];  // 131072 bytes: 4 ring slots x (A 16K + B 16K)

  const int gid = blockIdx.x;
  const int xcd = gid & 7;
  const int idx = gid >> 3;          // 0..31
  const int which = idx & 1;
  const int r = idx >> 1;            // 0..15
  const int tm = (xcd & 1) * 4 + (r & 3);
  const int tn = (xcd >> 1) * 4 + (r >> 2);

  const uint16_t* Bmat = which ? Bk : Bq;
  uint16_t* C = which ? Ck : Cq;
  const int m0 = tm * 256, n0 = tn * 256;

  const int t = threadIdx.x;
  const int lane = t & 63;
  const int w = t >> 6;              // 0..15
  const int wm = w >> 2, wn = w & 3; // 4x4 wave grid, each 64x64 output
  const int t16 = t * 16;

  const int gsw = (((t & 3) ^ ((t >> 3) & 3)) * 8);
  const uint16_t* aptr = A    + (size_t)(m0 + (t >> 2)) * 4096 + gsw;
  const uint16_t* bptr = Bmat + (size_t)(n0 + (t >> 2)) * 4096 + gsw;

  const int sl = ((lane >> 4) ^ ((lane & 15) >> 1)) & 3;
  const int aoff = (wm * 64 + (lane & 15)) * 64 + sl * 16;
  const int boff = (wn * 64 + (lane & 15)) * 64 + sl * 16;

  f32x4 acc[4][4] = {};

#pragma unroll
  for (int p = 0; p < 3; ++p) {
    GLOAD_LDS16(aptr + (size_t)p * 32, lds + p * 32768 + t16);
    GLOAD_LDS16(bptr + (size_t)p * 32, lds + p * 32768 + 16384 + t16);
  }
  asm volatile("s_waitcnt vmcnt(4)" ::: "memory");
  PH_BAR();

  for (int kt = 0; kt < 125; ++kt) {
    KTILE(kt, 1);
    asm volatile("s_waitcnt vmcnt(4)" ::: "memory");
    PH_BAR();
  }
  KTILE(125, 0);
  asm volatile("s_waitcnt vmcnt(2)" ::: "memory");
  PH_BAR();
  KTILE(126, 0);
  asm volatile("s_waitcnt vmcnt(0)" ::: "memory");
  PH_BAR();
  KTILE(127, 0);

  // epilogue: C/D layout col=lane&15, row=(lane>>4)*4+j ; store bf16
  const int colb = n0 + wn * 64 + (lane & 15);
  const int rowb = m0 + wm * 64 + (lane >> 4) * 4;
#pragma unroll
  for (int m_ = 0; m_ < 4; ++m_)
#pragma unroll
    for (int n_ = 0; n_ < 4; ++n_)
#pragma unroll
      for (int j = 0; j < 4; ++j)
        C[(size_t)(rowb + m_ * 16 + j) * 4096 + colb + n_ * 16] =
            f2bf_rne(acc[m_][n_][j]);
}

// ---------------- MFMA scores + softmax -> attn[256][64][64] f32 ------------
__device__ __forceinline__ bf16x8 load_frag_rot(const uint16_t* buf,
                                                int ij, int thb) {
  union { uint16_t u[8]; bf16x8 v; } r;
#pragma unroll
  for (int e = 0; e < 8; ++e) {
    const int th = thb + e;
    const int rot = (th + 2 * (th >> 3)) & 7;
    const int irot = (ij + rot * 8) & 63;
    r.u[e] = buf[th * 64 + irot];
  }
  return r.v;
}

__global__ __launch_bounds__(256) void attn_scores_mfma(
    const uint16_t* __restrict__ Qb, const uint16_t* __restrict__ Kb,
    float* __restrict__ attn) {
  const int n = blockIdx.x;
  __shared__ uint16_t q_l[2][4096];
  __shared__ uint16_t k_l[2][4096];
  __shared__ float scores_l[64 * 68];

  const int t = threadIdx.x;
  const int lane = t & 63;
  const int w = t >> 6;
  const int i0w = (w >> 1) * 32, j0w = (w & 1) * 32;

  const uint16_t* Qn = Qb + (size_t)n * 32768;
  const uint16_t* Kn = Kb + (size_t)n * 32768;

  const int g1 = t, g2 = t + 256;
  const int th1 = g1 >> 3, th2 = g2 >> 3;
  const int s1 = (((g1 & 7) - ((th1 + 2 * (th1 >> 3)) & 7)) & 7);
  const int s2 = (((g2 & 7) - ((th2 + 2 * (th2 >> 3)) & 7)) & 7);
  const size_t so1 = (size_t)th1 * 64 + s1 * 8;
  const size_t so2 = (size_t)th2 * 64 + s2 * 8;

#define STAGE_CH(bf, cm)                                                    \
  do {                                                                      \
    const size_t co_ = (size_t)(cm) * 4096;                                 \
    GLOAD_LDS16(Qn + co_ + so1, (char*)&q_l[bf][0] + g1 * 16);              \
    GLOAD_LDS16(Qn + co_ + so2, (char*)&q_l[bf][0] + g2 * 16);              \
    GLOAD_LDS16(Kn + co_ + so1, (char*)&k_l[bf][0] + g1 * 16);              \
    GLOAD_LDS16(Kn + co_ + so2, (char*)&k_l[bf][0] + g2 * 16);              \
  } while (0)

  f32x4 acc[2][2] = {};

  STAGE_CH(0, 0);
  asm volatile("s_waitcnt vmcnt(0)" ::: "memory");
  __syncthreads();

  for (int cm = 0; cm < 8; ++cm) {
    const int bf = cm & 1;
    if (cm < 7) STAGE_CH(bf ^ 1, cm + 1);
#pragma unroll
    for (int ks = 0; ks < 2; ++ks) {
      const int thb = ks * 32 + (lane >> 4) * 8;
      bf16x8 aa0 = load_frag_rot(&q_l[bf][0], i0w + (lane & 15), thb);
      bf16x8 aa1 = load_frag_rot(&q_l[bf][0], i0w + 16 + (lane & 15), thb);
      bf16x8 bb0 = load_frag_rot(&k_l[bf][0], j0w + (lane & 15), thb);
      bf16x8 bb1 = load_frag_rot(&k_l[bf][0], j0w + 16 + (lane & 15), thb);
      acc[0][0] = __builtin_amdgcn_mfma_f32_16x16x32_bf16(aa0, bb0, acc[0][0], 0, 0, 0);
      acc[0][1] = __builtin_amdgcn_mfma_f32_16x16x32_bf16(aa0, bb1, acc[0][1], 0, 0, 0);
      acc[1][0] = __builtin_amdgcn_mfma_f32_16x16x32_bf16(aa1, bb0, acc[1][0], 0, 0, 0);
      acc[1][1] = __builtin_amdgcn_mfma_f32_16x16x32_bf16(aa1, bb1, acc[1][1], 0, 0, 0);
    }
    asm volatile("s_waitcnt vmcnt(0)" ::: "memory");
    __syncthreads();
  }
#undef STAGE_CH

#pragma unroll
  for (int fi = 0; fi < 2; ++fi)
#pragma unroll
    for (int fj = 0; fj < 2; ++fj)
#pragma unroll
      for (int jr = 0; jr < 4; ++jr) {
        const int i = i0w + fi * 16 + (lane >> 4) * 4 + jr;
        const int j = j0w + fj * 16 + (lane & 15);
        scores_l[i * 68 + j] = acc[fi][fj][jr];
      }
  __syncthreads();

  {
    const int i = t >> 2, jg = t & 3;
    float pv[16];
    *(float4*)(pv + 0)  = *(const float4*)&scores_l[i * 68 + jg * 16 + 0];
    *(float4*)(pv + 4)  = *(const float4*)&scores_l[i * 68 + jg * 16 + 4];
    *(float4*)(pv + 8)  = *(const float4*)&scores_l[i * 68 + jg * 16 + 8];
    *(float4*)(pv + 12) = *(const float4*)&scores_l[i * 68 + jg * 16 + 12];
    float m = pv[0];
#pragma unroll
    for (int q = 1; q < 16; ++q) m = fmaxf(m, pv[q]);
    m = fmaxf(m, __shfl_xor(m, 1, 64));
    m = fmaxf(m, __shfl_xor(m, 2, 64));
    const float sc = 0.044194173824159216f * 1.4426950408889634f;
    float e[16];
    float ssum = 0.f;
#pragma unroll
    for (int q = 0; q < 16; ++q) {
      e[q] = exp2f((pv[q] - m) * sc);
      ssum += e[q];
    }
    ssum += __shfl_xor(ssum, 1, 64);
    ssum += __shfl_xor(ssum, 2, 64);
    const float inv = 1.0f / ssum;
    float ov[16];
#pragma unroll
    for (int q = 0; q < 16; ++q) ov[q] = e[q] * inv;
    float* dst = attn + (size_t)n * 4096 + i * 64 + jg * 16;
    *(float4*)(dst + 0)  = *(float4*)(ov + 0);
    *(float4*)(dst + 4)  = *(float4*)(ov + 4);
    *(float4*)(dst + 8)  = *(float4*)(ov + 8);
    *(float4*)(dst + 12) = *(float4*)(ov + 12);
  }
}

// ---------------- ctx via MFMA: V = Wv@x-slab ; out = V@attn ; leaky --------
// R16 rewrite: old ctx was LDS-bound (~4.5 GB LDS traffic from scalar b32
// re-reads, ~57us). MFMA fragment reuse cuts LDS bytes ~17x. Layouts (all
// bf16, rows padded to 72 elems = 144 B -> frag reads 2-way conflict-free):
//   xw[ul][cc], wv[e][cc], at[j][e]; MFMA1 D1[e][u] -> vt[u][e] (transposed
//   ushort4 store); MFMA2 D2[u][j]; leaky; float4 scatter (u contig in jr).
__global__ __launch_bounds__(256) void ctx_mfma(
    const float* __restrict__ x, const float* __restrict__ Wv,
    const float* __restrict__ attn, float* __restrict__ out) {
  const int n = blockIdx.x >> 3, ut = blockIdx.x & 7;
  const int b = n >> 3, g = n & 7;
  const int u0 = ut * 64;
  __shared__ uint16_t xw_l[64 * 72];
  __shared__ uint16_t wv_l[64 * 72];
  __shared__ uint16_t at_l[64 * 72];
  __shared__ uint16_t vt_l[64 * 72];
  const int t = threadIdx.x;
  const int lane = t & 63;
  const int w = t >> 6;

  {  // x[b, cc, g*512+u0+ul] -> xw_l[ul][cc]
    const float* xbase = x + (size_t)b * 262144 + (size_t)g * 512 + u0;
    const int cc = t >> 4, ul4 = (t & 15) * 4;
#pragma unroll
    for (int r = 0; r < 4; ++r) {
      int c = cc + r * 16;
      float4 v = *(const float4*)&xbase[(size_t)c * 4096 + ul4];
      xw_l[(ul4 + 0) * 72 + c] = f2bf_rne(v.x);
      xw_l[(ul4 + 1) * 72 + c] = f2bf_rne(v.y);
      xw_l[(ul4 + 2) * 72 + c] = f2bf_rne(v.z);
      xw_l[(ul4 + 3) * 72 + c] = f2bf_rne(v.w);
    }
  }
  {  // Wv[e][cc] -> wv_l[e][cc]
    const int e = t >> 4, cc4 = (t & 15) * 4;
#pragma unroll
    for (int r = 0; r < 4; ++r) {
      int ee = e + r * 16;
      float4 v = *(const float4*)&Wv[ee * 64 + cc4];
      ushort4 p;
      p.x = f2bf_rne(v.x); p.y = f2bf_rne(v.y);
      p.z = f2bf_rne(v.z); p.w = f2bf_rne(v.w);
      *(ushort4*)&wv_l[ee * 72 + cc4] = p;
    }
  }
  {  // attn[n][e][j] -> at_l[j][e]
    const float* an = attn + (size_t)n * 4096;
    const int e = t >> 4, j4 = (t & 15) * 4;
#pragma unroll
    for (int r = 0; r < 4; ++r) {
      int ee = e + r * 16;
      float4 v = *(const float4*)&an[ee * 64 + j4];
      at_l[(j4 + 0) * 72 + ee] = f2bf_rne(v.x);
      at_l[(j4 + 1) * 72 + ee] = f2bf_rne(v.y);
      at_l[(j4 + 2) * 72 + ee] = f2bf_rne(v.z);
      at_l[(j4 + 3) * 72 + ee] = f2bf_rne(v.w);
    }
  }
  __syncthreads();

  // MFMA1: D1[e][u] = sum_cc Wv[e][cc] * x[cc][u]; wave w owns e-tile w
  f32x4 acc1[4] = {};
#pragma unroll
  for (int ks = 0; ks < 2; ++ks) {
    bf16x8 a1 = *(const bf16x8*)&wv_l[(w * 16 + (lane & 15)) * 72 +
                                      ks * 32 + (lane >> 4) * 8];
#pragma unroll
    for (int nt = 0; nt < 4; ++nt) {
      bf16x8 b1 = *(const bf16x8*)&xw_l[(nt * 16 + (lane & 15)) * 72 +
                                        ks * 32 + (lane >> 4) * 8];
      acc1[nt] = __builtin_amdgcn_mfma_f32_16x16x32_bf16(a1, b1, acc1[nt], 0, 0, 0);
    }
  }
  // store V transposed: vt_l[u][e], 4 consecutive e per lane -> ushort4
#pragma unroll
  for (int nt = 0; nt < 4; ++nt) {
    int u = nt * 16 + (lane & 15);
    int e0 = w * 16 + (lane >> 4) * 4;
    ushort4 p;
    p.x = f2bf_rne(acc1[nt][0]); p.y = f2bf_rne(acc1[nt][1]);
    p.z = f2bf_rne(acc1[nt][2]); p.w = f2bf_rne(acc1[nt][3]);
    *(ushort4*)&vt_l[u * 72 + e0] = p;
  }
  __syncthreads();

  // MFMA2: D2[u][j] = sum_e V[u][e] * attn[e][j]; wave w owns u-tile w
  f32x4 acc2[4] = {};
#pragma unroll
  for (int ks = 0; ks < 2; ++ks) {
    bf16x8 a2 = *(const bf16x8*)&vt_l[(w * 16 + (lane & 15)) * 72 +
                                      ks * 32 + (lane >> 4) * 8];
#pragma unroll
    for (int nt = 0; nt < 4; ++nt) {
      bf16x8 b2 = *(const bf16x8*)&at_l[(nt * 16 + (lane & 15)) * 72 +
                                        ks * 32 + (lane >> 4) * 8];
      acc2[nt] = __builtin_amdgcn_mfma_f32_16x16x32_bf16(a2, b2, acc2[nt], 0, 0, 0);
    }
  }
  // epilogue: leaky + scatter; out[b, g*8+j/8, (j%8)*512 + u0 + u]
  float* ob = out + (size_t)b * 262144 + (size_t)g * 8 * 4096;
#pragma unroll
  for (int nt = 0; nt < 4; ++nt) {
    int j = nt * 16 + (lane & 15);
    int us = w * 16 + (lane >> 4) * 4;
    float4 o;
    o.x = acc2[nt][0] > 0.f ? acc2[nt][0] : 0.2f * acc2[nt][0];
    o.y = acc2[nt][1] > 0.f ? acc2[nt][1] : 0.2f * acc2[nt][1];
    o.z = acc2[nt][2] > 0.f ? acc2[nt][2] : 0.2f * acc2[nt][2];
    o.w = acc2[nt][3] > 0.f ? acc2[nt][3] : 0.2f * acc2[nt][3];
    *(float4*)&ob[(size_t)(j >> 3) * 4096 + (size_t)(j & 7) * 512 + u0 + us] = o;
  }
}

extern "C" void kernel_launch(void* const* d_in, const int* in_sizes, int n_in,
                              void* d_out, int out_size, void* d_ws, size_t ws_size,
                              hipStream_t stream) {
  const float* z  = (const float*)d_in[0];
  const float* x  = (const float*)d_in[1];
  const float* Wq = (const float*)d_in[2];
  const float* Wk = (const float*)d_in[3];
  const float* Wv = (const float*)d_in[4];
  float* out = (float*)d_out;

  char* ws = (char*)d_ws;
  uint16_t* zb   = (uint16_t*)(ws);                  // 16 MB bf16 z
  uint16_t* wqb  = (uint16_t*)(ws + 16777216);       // 32 MB bf16 Wq
  uint16_t* wkb  = (uint16_t*)(ws + 50331648);       // 32 MB bf16 Wk
  uint16_t* qbo  = (uint16_t*)(ws + 83886080);       // 16 MB bf16 Q
  uint16_t* kbo  = (uint16_t*)(ws + 100663296);      // 16 MB bf16 K
  float*    attn = (float*)(ws + 117440512);         // 4 MB f32

  cvt_all<<<20480, 256, 0, stream>>>(z, Wq, Wk, zb, wqb, wkb);

  (void)hipFuncSetAttribute((const void*)gemm_qk16,
                            hipFuncAttributeMaxDynamicSharedMemorySize, 131072);
  gemm_qk16<<<256, 1024, 131072, stream>>>(zb, wqb, wkb, qbo, kbo);

  attn_scores_mfma<<<256, 256, 0, stream>>>(qbo, kbo, attn);
  ctx_mfma<<<2048, 256, 0, stream>>>(x, Wv, attn, out);
}